// Round 13
// baseline (200.282 us; speedup 1.0000x reference)
//
#include <hip/hip_runtime.h>

#define LRELU(x) ((x) > 0.0f ? (x) : 0.2f * (x))
#define SB __builtin_amdgcn_sched_barrier(0)

typedef short bf16x8 __attribute__((ext_vector_type(8)));
typedef short bf16x4 __attribute__((ext_vector_type(4)));
typedef float f32x4 __attribute__((ext_vector_type(4)));

__device__ __forceinline__ short f2bf(float f) {
  union { float f; unsigned u; } x{f};
  return (short)((x.u + 0x7FFF + ((x.u >> 16) & 1)) >> 16);
}

// ---------------------------------------------------------------------------
// fused prologue: weight repack (float4-vectorized coalesced reads) +
// head-bias out init + border zeroing + x1-stat zeroing + conv0 (>= 2853).
__global__ __launch_bounds__(256) void k_repack_all(
    const float* __restrict__ w1, unsigned short* __restrict__ wr1,
    const float* __restrict__ w2, unsigned short* __restrict__ wr2,
    const float* __restrict__ bh, const int* __restrict__ sidx,
    float* __restrict__ out, unsigned short* __restrict__ x0t,
    unsigned short* __restrict__ ybf, const float* __restrict__ img,
    const float* __restrict__ w0, const float* __restrict__ b0,
    float* __restrict__ stat) {
  __shared__ float Ish[4 * 34];
  if (blockIdx.x >= 2853) {
    // ---- conv0 segment: img (B,1,128,128) -> x0t padded 66x66 NHWC bf16
    const int t = threadIdx.x;
    const int q = blockIdx.x - 2853;
    const int b = q >> 8, py = q & 255;
    const int oh = py >> 2, owb = (py & 3) << 4;
    const int s = sidx[b];
    const float* ip = img + (size_t)b * 16384;
    if (t < 136) {
      int r = t / 34, c = t % 34;
      int ih = 2 * oh - 1 + r, iw = 2 * owb - 1 + c;
      Ish[t] = ((unsigned)ih < 128u && (unsigned)iw < 128u) ? ip[ih * 128 + iw] : 0.f;
    }
    const int co = t & 63, ps = t >> 6;
    float wreg[16];
    const float* wp = w0 + (s * 64 + co) * 16;
#pragma unroll
    for (int i = 0; i < 16; i++) wreg[i] = wp[i];
    float bb = b0[s * 64 + co];
    __syncthreads();
    unsigned short* op = x0t + ((size_t)b * 4356 + (oh + 1) * 66 + (owb + 1)) * 64 + co;
#pragma unroll
    for (int j = 0; j < 4; j++) {
      int pl = ps * 4 + j;
      float acc = bb;
#pragma unroll
      for (int kh = 0; kh < 4; kh++)
#pragma unroll
        for (int kw = 0; kw < 4; kw++)
          acc += wreg[kh * 4 + kw] * Ish[kh * 34 + pl * 2 + kw];
      acc = LRELU(acc);
      op[pl * 64] = (unsigned short)f2bf(acc);
    }
    return;
  }
  int idx = blockIdx.x * 256 + threadIdx.x;
  if (idx < 131072) {
    float4 v = *(const float4*)(w1 + (size_t)idx * 4);
    int base = idx * 4;
    int tap0 = base & 15;
    int rest = base >> 4;
    int ci = rest & 63, sco = rest >> 6;
    unsigned short* d = wr1 + (size_t)sco * 1024 + ci;
    d[(tap0 + 0) * 64] = (unsigned short)f2bf(v.x);
    d[(tap0 + 1) * 64] = (unsigned short)f2bf(v.y);
    d[(tap0 + 2) * 64] = (unsigned short)f2bf(v.z);
    d[(tap0 + 3) * 64] = (unsigned short)f2bf(v.w);
    return;
  } else if (idx < 655360) {
    int i = idx - 131072;
    float4 v = *(const float4*)(w2 + (size_t)i * 4);
    int base = i * 4;
    int tap0 = base & 15;
    int rest = base >> 4;
    int ci = rest & 127, sco = rest >> 7;
    unsigned short* d = wr2 + (size_t)sco * 2048 + ci;
    d[(tap0 + 0) * 128] = (unsigned short)f2bf(v.x);
    d[(tap0 + 1) * 128] = (unsigned short)f2bf(v.y);
    d[(tap0 + 2) * 128] = (unsigned short)f2bf(v.z);
    d[(tap0 + 3) * 128] = (unsigned short)f2bf(v.w);
    return;
  } else if (idx < 658960) {
    int i = idx - 655360;
    if (i < 3600) out[i] = bh[sidx[i / 225]];
    return;
  } else if (idx < 692240) {
    int i = idx - 658960;
    int b = i / 2080, r = i % 2080;
    int pix = r >> 3, sub = r & 7;
    int row, col;
    if (pix < 66) { row = 0; col = pix; }
    else if (pix < 132) { row = 65; col = pix - 66; }
    else { int qq = pix - 132; row = 1 + (qq >> 1); col = (qq & 1) * 65; }
    bf16x8 z = {0, 0, 0, 0, 0, 0, 0, 0};
    *(bf16x8*)(x0t + ((size_t)b * 4356 + row * 66 + col) * 64 + sub * 8) = z;
    return;
  } else if (idx < 726032) {
    int i = idx - 692240;
    if (i >= 33792) return;
    int b = i / 2112, r = i % 2112;
    int pix = r >> 4, sub = r & 15;
    int row, col;
    if (pix < 34) { row = 0; col = pix; }
    else if (pix < 68) { row = 33; col = pix - 34; }
    else { int qq = pix - 68; row = 1 + (qq >> 1); col = (qq & 1) * 33; }
    bf16x8 z = {0, 0, 0, 0, 0, 0, 0, 0};
    *(bf16x8*)(ybf + ((size_t)b * 1156 + row * 34 + col) * 128 + sub * 8) = z;
    return;
  } else {
    int i = idx - 726032;
    if (i < 4096) stat[i] = 0.f;
    return;
  }
}

// ---------------------------------------------------------------------------
// conv1: LDS-staged MFMA GEMM + stat accumulation. 1-D grid 512, XCD-swizzled.
__global__ __launch_bounds__(256, 2) void k_conv1n(
    const unsigned short* __restrict__ x0t, const unsigned short* __restrict__ wr,
    const int* __restrict__ sidx, float* __restrict__ x1,
    float* __restrict__ stat) {
  __shared__ __align__(16) unsigned short Xs[26624];
  const int t = threadIdx.x;
  const int c = blockIdx.x & 7, rr = blockIdx.x >> 3;
  const int b = c + 8 * (rr >> 5);
  const int y = rr & 31;
  const int ne = y & 15;
  const int cog = y >> 4;
  const int s = sidx[b];
  const int lane = t & 63, wv = t >> 6;
  const int quad = lane >> 4, l16 = lane & 15;

  const unsigned short* gb = x0t + ((size_t)b * 4356 + 4 * ne * 66) * 64;
  {
    float4 v[13];
#pragma unroll
    for (int i = 0; i < 13; i++) v[i] = *(const float4*)(gb + (i * 256 + t) * 8);
#pragma unroll
    for (int i = 0; i < 13; i++) {
      int ba = (i * 256 + t) * 16;
      int sw = ba ^ (((ba >> 9) & 7) << 4);
      *(float4*)((char*)Xs + sw) = v[i];
    }
  }
  __syncthreads();

  const int co0w = cog * 64 + wv * 16;
  const unsigned short* ap = wr + ((size_t)(s * 128 + co0w + l16)) * 1024 + quad * 8;
  f32x4 acc[4];
#pragma unroll
  for (int nt = 0; nt < 4; nt++) acc[nt] = (f32x4){0.f, 0.f, 0.f, 0.f};

#pragma unroll
  for (int kc = 0; kc < 32; kc++) {
    const int tap = kc >> 1;
    const int cio = (kc & 1) * 32 + quad * 8;
    const int kh = tap >> 2, kw = tap & 3;
    bf16x8 af = *(const bf16x8*)(ap + kc * 32);
#pragma unroll
    for (int nt = 0; nt < 4; nt++) {
      int lr = 2 * (nt >> 1) + kh;
      int col = 2 * ((nt & 1) * 16 + l16) + kw;
      int ba = ((lr * 66 + col) * 64 + cio) * 2;
      int sw = ba ^ (((ba >> 9) & 7) << 4);
      bf16x8 bv = *(const bf16x8*)((const char*)Xs + sw);
      acc[nt] = __builtin_amdgcn_mfma_f32_16x16x32_bf16(af, bv, acc[nt], 0, 0, 0);
    }
  }

#pragma unroll
  for (int r = 0; r < 4; r++) {
    float sv = acc[0][r] + acc[1][r] + acc[2][r] + acc[3][r];
    float sq = acc[0][r] * acc[0][r] + acc[1][r] * acc[1][r] +
               acc[2][r] * acc[2][r] + acc[3][r] * acc[3][r];
#pragma unroll
    for (int o = 1; o < 16; o <<= 1) {
      sv += __shfl_xor(sv, o, 64);
      sq += __shfl_xor(sq, o, 64);
    }
    if (l16 == 0) {
      int co = co0w + quad * 4 + r;
      atomicAdd(&stat[(b * 128 + co) * 2 + 0], sv);
      atomicAdd(&stat[(b * 128 + co) * 2 + 1], sq);
    }
  }

#pragma unroll
  for (int nt = 0; nt < 4; nt++) {
    int p = ne * 64 + (nt >> 1) * 32 + (nt & 1) * 16 + l16;
#pragma unroll
    for (int r = 0; r < 4; r++)
      x1[((size_t)b * 128 + co0w + quad * 4 + r) * 1024 + p] = acc[nt][r];
  }
}

// ---------------------------------------------------------------------------
// fused q/k/v 1x1 projections over RAW x1 (lazy norm). 1-D grid 640,
// XCD-swizzled.
__global__ __launch_bounds__(256) void k_proj_qkv(
    const float* __restrict__ xin, const float* __restrict__ wq,
    const float* __restrict__ bq, const float* __restrict__ wk,
    const float* __restrict__ bk, const float* __restrict__ wv,
    const float* __restrict__ bv, const int* __restrict__ sidx,
    const float* __restrict__ stat,
    float* __restrict__ q, float* __restrict__ kout, unsigned short* __restrict__ vpk) {
  __shared__ float xsh[32 * 256];
  __shared__ float wsh[16 * 32];
  __shared__ float msh[128], ish[128];
  const int t = threadIdx.x;
  const int c = blockIdx.x & 7, rr = blockIdx.x >> 3;
  const int half = (rr >= 40) ? 1 : 0;
  const int b = c + 8 * half;
  const int y = rr - half * 40;
  const int s = sidx[b];
  const int cg = t >> 6, ng = t & 63;
  const float* w;
  const float* bias;
  int co0, nn0, CO;
  if (y < 8) {
    w = (y < 4) ? wq : wk;
    bias = (y < 4) ? bq : bk;
    co0 = 0;
    nn0 = (y & 3) * 256;
    CO = 16;
  } else {
    w = wv;
    bias = bv;
    co0 = ((y - 8) >> 2) * 16;
    nn0 = ((y - 8) & 3) * 256;
    CO = 128;
  }
  if (t < 128) {
    float sv = stat[(b * 128 + t) * 2 + 0];
    float sq = stat[(b * 128 + t) * 2 + 1];
    float m = sv * (1.0f / 1024.0f);
    float var = sq * (1.0f / 1024.0f) - m * m;
    msh[t] = m;
    ish[t] = rsqrtf(var + 1e-5f);
  }
  const float* xb = xin + (size_t)b * 128 * 1024;
  float4 acc4[4];
#pragma unroll
  for (int cix = 0; cix < 4; cix++) {
    float bb = bias[s * CO + co0 + cg * 4 + cix];
    acc4[cix] = make_float4(bb, bb, bb, bb);
  }
  __syncthreads();
  for (int cc = 0; cc < 4; cc++) {
#pragma unroll
    for (int k = 0; k < 8; k++) {
      int id = t + (k << 8);
      int ci = id >> 6, nf = id & 63;
      float4 v = ((const float4*)(xb + (cc * 32 + ci) * 1024 + nn0))[nf];
      float m = msh[cc * 32 + ci], iv = ish[cc * 32 + ci];
      v.x = (v.x - m) * iv; v.x = LRELU(v.x);
      v.y = (v.y - m) * iv; v.y = LRELU(v.y);
      v.z = (v.z - m) * iv; v.z = LRELU(v.z);
      v.w = (v.w - m) * iv; v.w = LRELU(v.w);
      ((float4*)xsh)[id] = v;
    }
    if (t < 128)
      ((float4*)wsh)[t] =
          ((const float4*)(w + ((size_t)(s * CO + co0 + (t >> 3))) * 128 + cc * 32))[t & 7];
    __syncthreads();
#pragma unroll
    for (int ci4 = 0; ci4 < 8; ci4++) {
      float4 wvv[4], xv[4];
#pragma unroll
      for (int cix = 0; cix < 4; cix++) wvv[cix] = ((const float4*)wsh)[(cg * 4 + cix) * 8 + ci4];
#pragma unroll
      for (int i = 0; i < 4; i++) xv[i] = ((const float4*)xsh)[(ci4 * 4 + i) * 64 + ng];
#pragma unroll
      for (int cix = 0; cix < 4; cix++)
#pragma unroll
        for (int i = 0; i < 4; i++) {
          float wvc = i == 0 ? wvv[cix].x : i == 1 ? wvv[cix].y : i == 2 ? wvv[cix].z : wvv[cix].w;
          acc4[cix].x += wvc * xv[i].x;
          acc4[cix].y += wvc * xv[i].y;
          acc4[cix].z += wvc * xv[i].z;
          acc4[cix].w += wvc * xv[i].w;
        }
    }
    __syncthreads();
  }
  if (y < 8) {
    float* outp = (y < 4) ? q : kout;
#pragma unroll
    for (int cix = 0; cix < 4; cix++)
      ((float4*)(outp + ((size_t)b * 16 + cg * 4 + cix) * 1024 + nn0))[ng] = acc4[cix];
  } else {
    int n = nn0 + ng * 4;
#pragma unroll
    for (int cix = 0; cix < 4; cix++) {
      int co = co0 + cg * 4 + cix;
      bf16x4 u;
      u[0] = f2bf(acc4[cix].x);
      u[1] = f2bf(acc4[cix].y);
      u[2] = f2bf(acc4[cix].z);
      u[3] = f2bf(acc4[cix].w);
      *(bf16x4*)(vpk + (((size_t)b * 32 + (n >> 5)) * 128 + co) * 32 + (n & 31)) = u;
    }
  }
}

// ---------------------------------------------------------------------------
// fused self-attention; QK^T now MFMA-based (bf16, K staged transposed in LDS,
// upper 16 K-channels zeroed). PV + epilogue unchanged. 1-D grid 1024,
// XCD-swizzled.
__global__ __launch_bounds__(256, 2) void k_attn(
    const float* __restrict__ q, const float* __restrict__ k,
    const unsigned short* __restrict__ vpk, const float* __restrict__ x1,
    const float* __restrict__ gamma, const int* __restrict__ sidx,
    const float* __restrict__ stat, unsigned short* __restrict__ ybf) {
  __shared__ __align__(16) short Psh[16 * 1032];
  __shared__ __align__(16) unsigned short Ks[16384];  // Ks[m][c] bf16, 16 c/row
  __shared__ float redm[64], reds[64];
  const int t = threadIdx.x;
  const int c = blockIdx.x & 7, rr = blockIdx.x >> 3;
  const int b = c + 8 * (rr >> 6);
  const int n0 = (rr & 63) << 4;
  const int lane = t & 63, wv = t >> 6;
  const int quad = lane >> 4, l16 = lane & 15;
  const float* qb = q + (size_t)b * 16 * 1024;
  const float* kb = k + (size_t)b * 16 * 1024;
  const float* xb = x1 + (size_t)b * 128 * 1024;

  // ---- Q B-fragment in registers: lane holds q[kdim=quad*8+i][n0+l16] ----
  bf16x8 qf = {0, 0, 0, 0, 0, 0, 0, 0};
  if (quad < 2) {
#pragma unroll
    for (int i = 0; i < 8; i++)
      qf[i] = f2bf(qb[(size_t)(quad * 8 + i) * 1024 + n0 + l16]);
  }

  // ---- stage K transposed: Ks[m][c] bf16 (coalesced fp32 reads) ----
#pragma unroll
  for (int cg = 0; cg < 4; cg++) {
    float4 v0 = *(const float4*)(kb + (size_t)(cg * 4 + 0) * 1024 + 4 * t);
    float4 v1 = *(const float4*)(kb + (size_t)(cg * 4 + 1) * 1024 + 4 * t);
    float4 v2 = *(const float4*)(kb + (size_t)(cg * 4 + 2) * 1024 + 4 * t);
    float4 v3 = *(const float4*)(kb + (size_t)(cg * 4 + 3) * 1024 + 4 * t);
#pragma unroll
    for (int j = 0; j < 4; j++) {
      float a0 = j == 0 ? v0.x : j == 1 ? v0.y : j == 2 ? v0.z : v0.w;
      float a1 = j == 0 ? v1.x : j == 1 ? v1.y : j == 2 ? v1.z : v1.w;
      float a2 = j == 0 ? v2.x : j == 1 ? v2.y : j == 2 ? v2.z : v2.w;
      float a3 = j == 0 ? v3.x : j == 1 ? v3.y : j == 2 ? v3.z : v3.w;
      bf16x4 pk;
      pk[0] = f2bf(a0);
      pk[1] = f2bf(a1);
      pk[2] = f2bf(a2);
      pk[3] = f2bf(a3);
      *(bf16x4*)&Ks[(4 * t + j) * 16 + cg * 4] = pk;
    }
  }
  __syncthreads();

  // ---- QK^T via MFMA: wave wv covers m = wv*256 .. +255 (16 tiles) ----
  f32x4 sacc[16];
#pragma unroll
  for (int tt = 0; tt < 16; tt++) sacc[tt] = (f32x4){0.f, 0.f, 0.f, 0.f};
  const int mwb = wv * 256;
#pragma unroll
  for (int tt = 0; tt < 16; tt++) {
    bf16x8 afr = {0, 0, 0, 0, 0, 0, 0, 0};
    if (quad < 2)
      afr = *(const bf16x8*)&Ks[(mwb + tt * 16 + l16) * 16 + quad * 8];
    sacc[tt] = __builtin_amdgcn_mfma_f32_16x16x32_bf16(afr, qf, sacc[tt], 0, 0, 0);
  }
  // D layout: col(n)=l16, row(m within tile)=quad*4+r

  // ---- softmax over m for n=l16: in-thread + 2 shuffles + cross-wave LDS ---
  float lmax = sacc[0][0];
#pragma unroll
  for (int tt = 0; tt < 16; tt++)
#pragma unroll
    for (int r = 0; r < 4; r++) lmax = fmaxf(lmax, sacc[tt][r]);
  lmax = fmaxf(lmax, __shfl_xor(lmax, 16, 64));
  lmax = fmaxf(lmax, __shfl_xor(lmax, 32, 64));
  if (lane < 16) redm[wv * 16 + lane] = lmax;
  __syncthreads();
  float gmax = fmaxf(fmaxf(redm[l16], redm[16 + l16]), fmaxf(redm[32 + l16], redm[48 + l16]));

  float lsum = 0.f;
#pragma unroll
  for (int tt = 0; tt < 16; tt++) {
    bf16x4 pv4;
#pragma unroll
    for (int r = 0; r < 4; r++) {
      float e = __expf(sacc[tt][r] - gmax);
      lsum += e;
      pv4[r] = f2bf(e);
    }
    *(bf16x4*)&Psh[l16 * 1032 + mwb + tt * 16 + quad * 4] = pv4;
  }
  lsum += __shfl_xor(lsum, 16, 64);
  lsum += __shfl_xor(lsum, 32, 64);
  if (lane < 16) reds[wv * 16 + lane] = lsum;
  __syncthreads();

  // ---- PV (unchanged proven path) ----
  const unsigned short* vp =
      vpk + ((size_t)b * 32 * 128 + (size_t)(wv * 32 + l16)) * 32 + quad * 8;
  const short* prow = Psh + l16 * 1032 + quad * 8;
  f32x4 dacc[2];
  dacc[0] = (f32x4){0.f, 0.f, 0.f, 0.f};
  dacc[1] = (f32x4){0.f, 0.f, 0.f, 0.f};

  bf16x8 VA0[4], VA1[4], PAr[4];
  bf16x8 VB0[4], VB1[4], PBr[4];
#define LDV(V0, V1, PR, G)                                \
  _Pragma("unroll") for (int m4 = 0; m4 < 4; m4++) {      \
    int mt = (G) * 4 + m4;                                \
    V0[m4] = *(const bf16x8*)(vp + mt * 4096);            \
    V1[m4] = *(const bf16x8*)(vp + 512 + mt * 4096);      \
    PR[m4] = *(const bf16x8*)(prow + mt * 32);            \
  }                                                       \
  SB;
#define MMV(V0, V1, PR)                                                                      \
  _Pragma("unroll") for (int m4 = 0; m4 < 4; m4++) {                                         \
    dacc[0] = __builtin_amdgcn_mfma_f32_16x16x32_bf16(V0[m4], PR[m4], dacc[0], 0, 0, 0);     \
    dacc[1] = __builtin_amdgcn_mfma_f32_16x16x32_bf16(V1[m4], PR[m4], dacc[1], 0, 0, 0);     \
  }                                                                                          \
  SB;

  LDV(VA0, VA1, PAr, 0)
  LDV(VB0, VB1, PBr, 1)
  MMV(VA0, VA1, PAr) LDV(VA0, VA1, PAr, 2)
  MMV(VB0, VB1, PBr) LDV(VB0, VB1, PBr, 3)
  MMV(VA0, VA1, PAr) LDV(VA0, VA1, PAr, 4)
  MMV(VB0, VB1, PBr) LDV(VB0, VB1, PBr, 5)
  MMV(VA0, VA1, PAr) LDV(VA0, VA1, PAr, 6)
  MMV(VB0, VB1, PBr) LDV(VB0, VB1, PBr, 7)
  MMV(VA0, VA1, PAr)
  MMV(VB0, VB1, PBr)
#undef LDV
#undef MMV
  __syncthreads();

  float* Osh = (float*)Psh;
  short* Osh2 = Psh + 4352;
#pragma unroll
  for (int i = 0; i < 2; i++) {
    int cob = wv * 32 + i * 16 + quad * 4;
#pragma unroll
    for (int r = 0; r < 4; r++) Osh[(cob + r) * 17 + l16] = dacc[i][r];
  }
  __syncthreads();
  float g = gamma[sidx[b]];
  {
    int co = t >> 1, j0 = (t & 1) * 8;
    float sv = stat[(b * 128 + co) * 2 + 0];
    float sq = stat[(b * 128 + co) * 2 + 1];
    float mm = sv * (1.0f / 1024.0f);
    float iv = rsqrtf(sq * (1.0f / 1024.0f) - mm * mm + 1e-5f);
    const float* xr = xb + (co << 10) + n0 + j0;
    float4 xv0 = *(const float4*)xr;
    float4 xv1 = *(const float4*)(xr + 4);
    float xs[8] = {xv0.x, xv0.y, xv0.z, xv0.w, xv1.x, xv1.y, xv1.z, xv1.w};
#pragma unroll
    for (int j = 0; j < 8; j++) {
      float nv = (xs[j] - mm) * iv;
      xs[j] = LRELU(nv);
    }
#pragma unroll
    for (int j = 0; j < 8; j++) {
      int nl = j0 + j;
      float rs = 1.0f / (reds[nl] + reds[16 + nl] + reds[32 + nl] + reds[48 + nl]);
      Osh2[nl * 136 + co] = f2bf(g * Osh[co * 17 + nl] * rs + xs[j]);
    }
  }
  __syncthreads();
  {
    int nl = t >> 4, cg = t & 15;
    bf16x8 u = *(const bf16x8*)&Osh2[nl * 136 + cg * 8];
    int p = n0 + nl;
    int ih = p >> 5, iw = p & 31;
    *(bf16x8*)(ybf + ((size_t)b * 1156 + (ih + 1) * 34 + (iw + 1)) * 128 + cg * 8) = u;
  }
}

// ---------------------------------------------------------------------------
// conv2: LDS-staged MFMA GEMM. 1-D grid 512, XCD-swizzled like conv1.
__global__ __launch_bounds__(256, 2) void k_conv2n(
    const unsigned short* __restrict__ ybf, const unsigned short* __restrict__ wr,
    const int* __restrict__ sidx, float* __restrict__ x2) {
  __shared__ __align__(16) unsigned short Xs[26624];
  const int t = threadIdx.x;
  const int c = blockIdx.x & 7, rr = blockIdx.x >> 3;
  const int b = c + 8 * (rr >> 5);
  const int y = rr & 31;
  const int ne = y & 7;
  const int cog = y >> 3;
  const int s = sidx[b];
  const int lane = t & 63, wv = t >> 6;
  const int quad = lane >> 4, l16 = lane & 15;

  const unsigned short* gb = ybf + ((size_t)b * 1156 + 4 * ne * 34) * 128;
  {
    float4 v[13];
#pragma unroll
    for (int i = 0; i < 13; i++) v[i] = *(const float4*)(gb + (i * 256 + t) * 8);
#pragma unroll
    for (int i = 0; i < 13; i++) {
      int ba = (i * 256 + t) * 16;
      int sw = ba ^ (((ba >> 9) & 7) << 4);
      *(float4*)((char*)Xs + sw) = v[i];
    }
  }
  __syncthreads();

  const int co0w = cog * 64 + wv * 16;
  const unsigned short* ap = wr + ((size_t)(s * 256 + co0w + l16)) * 2048 + quad * 8;
  f32x4 acc[2];
  acc[0] = (f32x4){0.f, 0.f, 0.f, 0.f};
  acc[1] = (f32x4){0.f, 0.f, 0.f, 0.f};

#pragma unroll
  for (int kc = 0; kc < 64; kc++) {
    const int tap = kc >> 2;
    const int cio = (kc & 3) * 32 + quad * 8;
    const int kh = tap >> 2, kw = tap & 3;
    bf16x8 af = *(const bf16x8*)(ap + kc * 32);
#pragma unroll
    for (int nt = 0; nt < 2; nt++) {
      int lr = 2 * nt + kh;
      int col = 2 * l16 + kw;
      int ba = ((lr * 34 + col) * 128 + cio) * 2;
      int sw = ba ^ (((ba >> 9) & 7) << 4);
      bf16x8 bv = *(const bf16x8*)((const char*)Xs + sw);
      acc[nt] = __builtin_amdgcn_mfma_f32_16x16x32_bf16(af, bv, acc[nt], 0, 0, 0);
    }
  }

#pragma unroll
  for (int nt = 0; nt < 2; nt++) {
    int p = ne * 32 + nt * 16 + l16;
#pragma unroll
    for (int r = 0; r < 4; r++)
      x2[((size_t)b * 256 + co0w + quad * 4 + r) * 256 + p] = acc[nt][r];
  }
}

// ---------------------------------------------------------------------------
// head: x2 instance-norm (+leaky) FUSED into the head conv (x2 arrives RAW).
__global__ __launch_bounds__(256) void k_head_part(
    const float* __restrict__ x2, const float* __restrict__ wh,
    const int* __restrict__ sidx, float* __restrict__ out) {
  __shared__ float Xs[32 * 256];
  __shared__ float Wsh[512];
  __shared__ float sm[32], si[32];
  const int t = threadIdx.x;
  const int b = blockIdx.x, cc = blockIdx.y;
  const int s = sidx[b];
  const float* xp = x2 + ((size_t)b * 256 + cc * 32) * 256;
#pragma unroll
  for (int i = 0; i < 32; i++) Xs[i * 256 + t] = xp[i * 256 + t];
#pragma unroll
  for (int i = 0; i < 2; i++) {
    int idx = i * 256 + t;
    Wsh[idx] = wh[s * 4096 + cc * 512 + idx];
  }
  __syncthreads();
  {
    int r = t >> 3, c0 = (t & 7) * 32;
    float sv = 0.f, sq = 0.f;
#pragma unroll
    for (int j = 0; j < 32; j++) {
      float v = Xs[r * 256 + c0 + j];
      sv += v;
      sq += v * v;
    }
#pragma unroll
    for (int o = 1; o < 8; o <<= 1) {
      sv += __shfl_xor(sv, o, 64);
      sq += __shfl_xor(sq, o, 64);
    }
    if ((t & 7) == 0) {
      float m = sv * (1.0f / 256.0f);
      float var = sq * (1.0f / 256.0f) - m * m;
      sm[r] = m;
      si[r] = rsqrtf(var + 1e-5f);
    }
  }
  __syncthreads();
#pragma unroll
  for (int i = 0; i < 32; i++) {
    float v = (Xs[i * 256 + t] - sm[i]) * si[i];
    Xs[i * 256 + t] = LRELU(v);
  }
  __syncthreads();
  if (t < 225) {
    int oh = t / 15, ow = t % 15;
    float acc = 0.0f;
    for (int ci = 0; ci < 32; ci++) {
      const float* xr = Xs + ci * 256;
      const float* wr = Wsh + ci * 16;
#pragma unroll
      for (int kh = 0; kh < 4; kh++) {
        int ih = oh - 1 + kh;
        if ((unsigned)ih >= 16u) continue;
#pragma unroll
        for (int kw = 0; kw < 4; kw++) {
          int iw = ow - 1 + kw;
          if ((unsigned)iw >= 16u) continue;
          acc += wr[kh * 4 + kw] * xr[(ih << 4) + iw];
        }
      }
    }
    atomicAdd(out + b * 225 + t, acc);
  }
}

// ---------------------------------------------------------------------------
extern "C" void kernel_launch(void* const* d_in, const int* in_sizes, int n_in,
                              void* d_out, int out_size, void* d_ws, size_t ws_size,
                              hipStream_t stream) {
  const float* img = (const float*)d_in[0];
  const int* sidx = (const int*)d_in[1];
  const float* w0 = (const float*)d_in[2];
  const float* b0 = (const float*)d_in[3];
  const float* w1 = (const float*)d_in[4];
  const float* w2 = (const float*)d_in[6];
  const float* wq = (const float*)d_in[8];
  const float* bq = (const float*)d_in[9];
  const float* wk = (const float*)d_in[10];
  const float* bk = (const float*)d_in[11];
  const float* wv = (const float*)d_in[12];
  const float* bv = (const float*)d_in[13];
  const float* gamma = (const float*)d_in[14];
  const float* wh = (const float*)d_in[15];
  const float* bh = (const float*)d_in[16];
  float* out = (float*)d_out;

  float* ws = (float*)d_ws;
  unsigned short* x0t = (unsigned short*)(ws);            // padded 66x66: 16*4356*64 shorts
  float* x1 = ws + 2359296;                               // [2.25M,4.25M)
  float* q = ws + 4456448;                                // [4.25M,4.5M)
  float* k = ws + 4718592;                                // [4.5M,4.75M)
  unsigned short* vpk = (unsigned short*)(ws + 4980736);  // [4.75M,5.75M)
  unsigned short* ybf = (unsigned short*)(ws + 6029312);  // padded 34x34: 16*1156*128 shorts
  float* x2 = ws + 7340032;                               // [7M,8M)
  float* stat = ws + 8650752;                             // [8.25M,+4096) x1 norm stats
  unsigned short* wr1 = (unsigned short*)(ws + 8912896);  // [8.5M,8.75M)
  unsigned short* wr2 = (unsigned short*)(ws + 9175040);  // [8.75M,9.75M)

  k_repack_all<<<6949, 256, 0, stream>>>(w1, wr1, w2, wr2, bh, sidx, out, x0t, ybf,
                                         img, w0, b0, stat);
  k_conv1n<<<512, 256, 0, stream>>>(x0t, wr1, sidx, x1, stat);
  k_proj_qkv<<<640, 256, 0, stream>>>(x1, wq, bq, wk, bk, wv, bv, sidx, stat, q, k, vpk);
  k_attn<<<1024, 256, 0, stream>>>(q, k, vpk, x1, gamma, sidx, stat, ybf);
  k_conv2n<<<512, 256, 0, stream>>>(ybf, wr2, sidx, x2);
  k_head_part<<<dim3(16, 8), 256, 0, stream>>>(x2, wh, sidx, out);
}

// Round 14
// 197.796 us; speedup vs baseline: 1.0126x; 1.0126x over previous
//
#include <hip/hip_runtime.h>

#define LRELU(x) ((x) > 0.0f ? (x) : 0.2f * (x))
#define SB __builtin_amdgcn_sched_barrier(0)

typedef short bf16x8 __attribute__((ext_vector_type(8)));
typedef short bf16x4 __attribute__((ext_vector_type(4)));
typedef float f32x4 __attribute__((ext_vector_type(4)));

__device__ __forceinline__ short f2bf(float f) {
  union { float f; unsigned u; } x{f};
  return (short)((x.u + 0x7FFF + ((x.u >> 16) & 1)) >> 16);
}

// ---------------------------------------------------------------------------
// fused prologue: weight repack (float4-vectorized coalesced reads) +
// head-bias out init + border zeroing + x1-stat zeroing + conv0 (>= 2853).
__global__ __launch_bounds__(256) void k_repack_all(
    const float* __restrict__ w1, unsigned short* __restrict__ wr1,
    const float* __restrict__ w2, unsigned short* __restrict__ wr2,
    const float* __restrict__ bh, const int* __restrict__ sidx,
    float* __restrict__ out, unsigned short* __restrict__ x0t,
    unsigned short* __restrict__ ybf, const float* __restrict__ img,
    const float* __restrict__ w0, const float* __restrict__ b0,
    float* __restrict__ stat) {
  __shared__ float Ish[4 * 34];
  if (blockIdx.x >= 2853) {
    // ---- conv0 segment: img (B,1,128,128) -> x0t padded 66x66 NHWC bf16
    const int t = threadIdx.x;
    const int q = blockIdx.x - 2853;
    const int b = q >> 8, py = q & 255;
    const int oh = py >> 2, owb = (py & 3) << 4;
    const int s = sidx[b];
    const float* ip = img + (size_t)b * 16384;
    if (t < 136) {
      int r = t / 34, c = t % 34;
      int ih = 2 * oh - 1 + r, iw = 2 * owb - 1 + c;
      Ish[t] = ((unsigned)ih < 128u && (unsigned)iw < 128u) ? ip[ih * 128 + iw] : 0.f;
    }
    const int co = t & 63, ps = t >> 6;
    float wreg[16];
    const float* wp = w0 + (s * 64 + co) * 16;
#pragma unroll
    for (int i = 0; i < 16; i++) wreg[i] = wp[i];
    float bb = b0[s * 64 + co];
    __syncthreads();
    unsigned short* op = x0t + ((size_t)b * 4356 + (oh + 1) * 66 + (owb + 1)) * 64 + co;
#pragma unroll
    for (int j = 0; j < 4; j++) {
      int pl = ps * 4 + j;
      float acc = bb;
#pragma unroll
      for (int kh = 0; kh < 4; kh++)
#pragma unroll
        for (int kw = 0; kw < 4; kw++)
          acc += wreg[kh * 4 + kw] * Ish[kh * 34 + pl * 2 + kw];
      acc = LRELU(acc);
      op[pl * 64] = (unsigned short)f2bf(acc);
    }
    return;
  }
  int idx = blockIdx.x * 256 + threadIdx.x;
  if (idx < 131072) {
    float4 v = *(const float4*)(w1 + (size_t)idx * 4);
    int base = idx * 4;
    int tap0 = base & 15;
    int rest = base >> 4;
    int ci = rest & 63, sco = rest >> 6;
    unsigned short* d = wr1 + (size_t)sco * 1024 + ci;
    d[(tap0 + 0) * 64] = (unsigned short)f2bf(v.x);
    d[(tap0 + 1) * 64] = (unsigned short)f2bf(v.y);
    d[(tap0 + 2) * 64] = (unsigned short)f2bf(v.z);
    d[(tap0 + 3) * 64] = (unsigned short)f2bf(v.w);
    return;
  } else if (idx < 655360) {
    int i = idx - 131072;
    float4 v = *(const float4*)(w2 + (size_t)i * 4);
    int base = i * 4;
    int tap0 = base & 15;
    int rest = base >> 4;
    int ci = rest & 127, sco = rest >> 7;
    unsigned short* d = wr2 + (size_t)sco * 2048 + ci;
    d[(tap0 + 0) * 128] = (unsigned short)f2bf(v.x);
    d[(tap0 + 1) * 128] = (unsigned short)f2bf(v.y);
    d[(tap0 + 2) * 128] = (unsigned short)f2bf(v.z);
    d[(tap0 + 3) * 128] = (unsigned short)f2bf(v.w);
    return;
  } else if (idx < 658960) {
    int i = idx - 655360;
    if (i < 3600) out[i] = bh[sidx[i / 225]];
    return;
  } else if (idx < 692240) {
    int i = idx - 658960;
    int b = i / 2080, r = i % 2080;
    int pix = r >> 3, sub = r & 7;
    int row, col;
    if (pix < 66) { row = 0; col = pix; }
    else if (pix < 132) { row = 65; col = pix - 66; }
    else { int qq = pix - 132; row = 1 + (qq >> 1); col = (qq & 1) * 65; }
    bf16x8 z = {0, 0, 0, 0, 0, 0, 0, 0};
    *(bf16x8*)(x0t + ((size_t)b * 4356 + row * 66 + col) * 64 + sub * 8) = z;
    return;
  } else if (idx < 726032) {
    int i = idx - 692240;
    if (i >= 33792) return;
    int b = i / 2112, r = i % 2112;
    int pix = r >> 4, sub = r & 15;
    int row, col;
    if (pix < 34) { row = 0; col = pix; }
    else if (pix < 68) { row = 33; col = pix - 34; }
    else { int qq = pix - 68; row = 1 + (qq >> 1); col = (qq & 1) * 33; }
    bf16x8 z = {0, 0, 0, 0, 0, 0, 0, 0};
    *(bf16x8*)(ybf + ((size_t)b * 1156 + row * 34 + col) * 128 + sub * 8) = z;
    return;
  } else {
    int i = idx - 726032;
    if (i < 4096) stat[i] = 0.f;
    return;
  }
}

// ---------------------------------------------------------------------------
// conv1: LDS-staged MFMA GEMM + stat accumulation. 1-D grid 512, XCD-swizzled.
__global__ __launch_bounds__(256, 2) void k_conv1n(
    const unsigned short* __restrict__ x0t, const unsigned short* __restrict__ wr,
    const int* __restrict__ sidx, float* __restrict__ x1,
    float* __restrict__ stat) {
  __shared__ __align__(16) unsigned short Xs[26624];
  const int t = threadIdx.x;
  const int c = blockIdx.x & 7, rr = blockIdx.x >> 3;
  const int b = c + 8 * (rr >> 5);
  const int y = rr & 31;
  const int ne = y & 15;
  const int cog = y >> 4;
  const int s = sidx[b];
  const int lane = t & 63, wv = t >> 6;
  const int quad = lane >> 4, l16 = lane & 15;

  const unsigned short* gb = x0t + ((size_t)b * 4356 + 4 * ne * 66) * 64;
  {
    float4 v[13];
#pragma unroll
    for (int i = 0; i < 13; i++) v[i] = *(const float4*)(gb + (i * 256 + t) * 8);
#pragma unroll
    for (int i = 0; i < 13; i++) {
      int ba = (i * 256 + t) * 16;
      int sw = ba ^ (((ba >> 9) & 7) << 4);
      *(float4*)((char*)Xs + sw) = v[i];
    }
  }
  __syncthreads();

  const int co0w = cog * 64 + wv * 16;
  const unsigned short* ap = wr + ((size_t)(s * 128 + co0w + l16)) * 1024 + quad * 8;
  f32x4 acc[4];
#pragma unroll
  for (int nt = 0; nt < 4; nt++) acc[nt] = (f32x4){0.f, 0.f, 0.f, 0.f};

#pragma unroll
  for (int kc = 0; kc < 32; kc++) {
    const int tap = kc >> 1;
    const int cio = (kc & 1) * 32 + quad * 8;
    const int kh = tap >> 2, kw = tap & 3;
    bf16x8 af = *(const bf16x8*)(ap + kc * 32);
#pragma unroll
    for (int nt = 0; nt < 4; nt++) {
      int lr = 2 * (nt >> 1) + kh;
      int col = 2 * ((nt & 1) * 16 + l16) + kw;
      int ba = ((lr * 66 + col) * 64 + cio) * 2;
      int sw = ba ^ (((ba >> 9) & 7) << 4);
      bf16x8 bv = *(const bf16x8*)((const char*)Xs + sw);
      acc[nt] = __builtin_amdgcn_mfma_f32_16x16x32_bf16(af, bv, acc[nt], 0, 0, 0);
    }
  }

#pragma unroll
  for (int r = 0; r < 4; r++) {
    float sv = acc[0][r] + acc[1][r] + acc[2][r] + acc[3][r];
    float sq = acc[0][r] * acc[0][r] + acc[1][r] * acc[1][r] +
               acc[2][r] * acc[2][r] + acc[3][r] * acc[3][r];
#pragma unroll
    for (int o = 1; o < 16; o <<= 1) {
      sv += __shfl_xor(sv, o, 64);
      sq += __shfl_xor(sq, o, 64);
    }
    if (l16 == 0) {
      int co = co0w + quad * 4 + r;
      atomicAdd(&stat[(b * 128 + co) * 2 + 0], sv);
      atomicAdd(&stat[(b * 128 + co) * 2 + 1], sq);
    }
  }

#pragma unroll
  for (int nt = 0; nt < 4; nt++) {
    int p = ne * 64 + (nt >> 1) * 32 + (nt & 1) * 16 + l16;
#pragma unroll
    for (int r = 0; r < 4; r++)
      x1[((size_t)b * 128 + co0w + quad * 4 + r) * 1024 + p] = acc[nt][r];
  }
}

// ---------------------------------------------------------------------------
// fused q/k/v 1x1 projections over RAW x1 (lazy norm). q/k are emitted as
// PRE-PACKED bf16 MFMA fragments: qbf[b][n][c], kbf[b][m][c] (16 c per row).
// 1-D grid 640, XCD-swizzled.
__global__ __launch_bounds__(256) void k_proj_qkv(
    const float* __restrict__ xin, const float* __restrict__ wq,
    const float* __restrict__ bq, const float* __restrict__ wk,
    const float* __restrict__ bk, const float* __restrict__ wv,
    const float* __restrict__ bv, const int* __restrict__ sidx,
    const float* __restrict__ stat,
    unsigned short* __restrict__ qbf, unsigned short* __restrict__ kbf,
    unsigned short* __restrict__ vpk) {
  __shared__ float xsh[32 * 256];
  __shared__ float wsh[16 * 32];
  __shared__ float msh[128], ish[128];
  const int t = threadIdx.x;
  const int c = blockIdx.x & 7, rr = blockIdx.x >> 3;
  const int half = (rr >= 40) ? 1 : 0;
  const int b = c + 8 * half;
  const int y = rr - half * 40;
  const int s = sidx[b];
  const int cg = t >> 6, ng = t & 63;
  const float* w;
  const float* bias;
  int co0, nn0, CO;
  if (y < 8) {
    w = (y < 4) ? wq : wk;
    bias = (y < 4) ? bq : bk;
    co0 = 0;
    nn0 = (y & 3) * 256;
    CO = 16;
  } else {
    w = wv;
    bias = bv;
    co0 = ((y - 8) >> 2) * 16;
    nn0 = ((y - 8) & 3) * 256;
    CO = 128;
  }
  if (t < 128) {
    float sv = stat[(b * 128 + t) * 2 + 0];
    float sq = stat[(b * 128 + t) * 2 + 1];
    float m = sv * (1.0f / 1024.0f);
    float var = sq * (1.0f / 1024.0f) - m * m;
    msh[t] = m;
    ish[t] = rsqrtf(var + 1e-5f);
  }
  const float* xb = xin + (size_t)b * 128 * 1024;
  float4 acc4[4];
#pragma unroll
  for (int cix = 0; cix < 4; cix++) {
    float bb = bias[s * CO + co0 + cg * 4 + cix];
    acc4[cix] = make_float4(bb, bb, bb, bb);
  }
  __syncthreads();
  for (int cc = 0; cc < 4; cc++) {
#pragma unroll
    for (int k = 0; k < 8; k++) {
      int id = t + (k << 8);
      int ci = id >> 6, nf = id & 63;
      float4 v = ((const float4*)(xb + (cc * 32 + ci) * 1024 + nn0))[nf];
      float m = msh[cc * 32 + ci], iv = ish[cc * 32 + ci];
      v.x = (v.x - m) * iv; v.x = LRELU(v.x);
      v.y = (v.y - m) * iv; v.y = LRELU(v.y);
      v.z = (v.z - m) * iv; v.z = LRELU(v.z);
      v.w = (v.w - m) * iv; v.w = LRELU(v.w);
      ((float4*)xsh)[id] = v;
    }
    if (t < 128)
      ((float4*)wsh)[t] =
          ((const float4*)(w + ((size_t)(s * CO + co0 + (t >> 3))) * 128 + cc * 32))[t & 7];
    __syncthreads();
#pragma unroll
    for (int ci4 = 0; ci4 < 8; ci4++) {
      float4 wvv[4], xv[4];
#pragma unroll
      for (int cix = 0; cix < 4; cix++) wvv[cix] = ((const float4*)wsh)[(cg * 4 + cix) * 8 + ci4];
#pragma unroll
      for (int i = 0; i < 4; i++) xv[i] = ((const float4*)xsh)[(ci4 * 4 + i) * 64 + ng];
#pragma unroll
      for (int cix = 0; cix < 4; cix++)
#pragma unroll
        for (int i = 0; i < 4; i++) {
          float wvc = i == 0 ? wvv[cix].x : i == 1 ? wvv[cix].y : i == 2 ? wvv[cix].z : wvv[cix].w;
          acc4[cix].x += wvc * xv[i].x;
          acc4[cix].y += wvc * xv[i].y;
          acc4[cix].z += wvc * xv[i].z;
          acc4[cix].w += wvc * xv[i].w;
        }
    }
    __syncthreads();
  }
  if (y < 8) {
    // packed bf16 [n][c] store: for each of 4 n, the 4 c-values (co=cg*4..+3)
    unsigned short* outp = ((y < 4) ? qbf : kbf) + (size_t)b * 16384;
#pragma unroll
    for (int j = 0; j < 4; j++) {
      bf16x4 u;
#pragma unroll
      for (int cix = 0; cix < 4; cix++) {
        float v = j == 0 ? acc4[cix].x : j == 1 ? acc4[cix].y : j == 2 ? acc4[cix].z
                                                                       : acc4[cix].w;
        u[cix] = f2bf(v);
      }
      *(bf16x4*)(outp + (size_t)(nn0 + ng * 4 + j) * 16 + cg * 4) = u;
    }
  } else {
    int n = nn0 + ng * 4;
#pragma unroll
    for (int cix = 0; cix < 4; cix++) {
      int co = co0 + cg * 4 + cix;
      bf16x4 u;
      u[0] = f2bf(acc4[cix].x);
      u[1] = f2bf(acc4[cix].y);
      u[2] = f2bf(acc4[cix].z);
      u[3] = f2bf(acc4[cix].w);
      *(bf16x4*)(vpk + (((size_t)b * 32 + (n >> 5)) * 128 + co) * 32 + (n & 31)) = u;
    }
  }
}

// ---------------------------------------------------------------------------
// fused self-attention; MFMA QK^T with PRE-PACKED bf16 q/k fragments (no
// K staging, no LDS Ks). PV + epilogue unchanged. 1-D grid 1024, XCD-swizzled.
__global__ __launch_bounds__(256, 2) void k_attn(
    const unsigned short* __restrict__ qbf, const unsigned short* __restrict__ kbf,
    const unsigned short* __restrict__ vpk, const float* __restrict__ x1,
    const float* __restrict__ gamma, const int* __restrict__ sidx,
    const float* __restrict__ stat, unsigned short* __restrict__ ybf) {
  __shared__ __align__(16) short Psh[16 * 1032];
  __shared__ float redm[64], reds[64];
  const int t = threadIdx.x;
  const int c = blockIdx.x & 7, rr = blockIdx.x >> 3;
  const int b = c + 8 * (rr >> 6);
  const int n0 = (rr & 63) << 4;
  const int lane = t & 63, wv = t >> 6;
  const int quad = lane >> 4, l16 = lane & 15;
  const unsigned short* qbb = qbf + (size_t)b * 16384;
  const unsigned short* kbb = kbf + (size_t)b * 16384;
  const float* xb = x1 + (size_t)b * 128 * 1024;

  // ---- Q B-fragment: direct packed load (upper 16 k-channels zero) ----
  bf16x8 qf = {0, 0, 0, 0, 0, 0, 0, 0};
  if (quad < 2) qf = *(const bf16x8*)(qbb + (size_t)(n0 + l16) * 16 + quad * 8);

  // ---- QK^T via MFMA: wave wv covers m = wv*256 .. +255 (16 tiles) ----
  f32x4 sacc[16];
#pragma unroll
  for (int tt = 0; tt < 16; tt++) sacc[tt] = (f32x4){0.f, 0.f, 0.f, 0.f};
  const int mwb = wv * 256;
#pragma unroll
  for (int tt = 0; tt < 16; tt++) {
    bf16x8 afr = {0, 0, 0, 0, 0, 0, 0, 0};
    if (quad < 2)
      afr = *(const bf16x8*)(kbb + (size_t)(mwb + tt * 16 + l16) * 16 + quad * 8);
    sacc[tt] = __builtin_amdgcn_mfma_f32_16x16x32_bf16(afr, qf, sacc[tt], 0, 0, 0);
  }
  // D layout: col(n)=l16, row(m within tile)=quad*4+r

  // ---- softmax over m for n=l16: in-thread + 2 shuffles + cross-wave LDS ---
  float lmax = sacc[0][0];
#pragma unroll
  for (int tt = 0; tt < 16; tt++)
#pragma unroll
    for (int r = 0; r < 4; r++) lmax = fmaxf(lmax, sacc[tt][r]);
  lmax = fmaxf(lmax, __shfl_xor(lmax, 16, 64));
  lmax = fmaxf(lmax, __shfl_xor(lmax, 32, 64));
  if (lane < 16) redm[wv * 16 + lane] = lmax;
  __syncthreads();
  float gmax = fmaxf(fmaxf(redm[l16], redm[16 + l16]), fmaxf(redm[32 + l16], redm[48 + l16]));

  float lsum = 0.f;
#pragma unroll
  for (int tt = 0; tt < 16; tt++) {
    bf16x4 pv4;
#pragma unroll
    for (int r = 0; r < 4; r++) {
      float e = __expf(sacc[tt][r] - gmax);
      lsum += e;
      pv4[r] = f2bf(e);
    }
    *(bf16x4*)&Psh[l16 * 1032 + mwb + tt * 16 + quad * 4] = pv4;
  }
  lsum += __shfl_xor(lsum, 16, 64);
  lsum += __shfl_xor(lsum, 32, 64);
  if (lane < 16) reds[wv * 16 + lane] = lsum;
  __syncthreads();

  // ---- PV (unchanged proven path) ----
  const unsigned short* vp =
      vpk + ((size_t)b * 32 * 128 + (size_t)(wv * 32 + l16)) * 32 + quad * 8;
  const short* prow = Psh + l16 * 1032 + quad * 8;
  f32x4 dacc[2];
  dacc[0] = (f32x4){0.f, 0.f, 0.f, 0.f};
  dacc[1] = (f32x4){0.f, 0.f, 0.f, 0.f};

  bf16x8 VA0[4], VA1[4], PAr[4];
  bf16x8 VB0[4], VB1[4], PBr[4];
#define LDV(V0, V1, PR, G)                                \
  _Pragma("unroll") for (int m4 = 0; m4 < 4; m4++) {      \
    int mt = (G) * 4 + m4;                                \
    V0[m4] = *(const bf16x8*)(vp + mt * 4096);            \
    V1[m4] = *(const bf16x8*)(vp + 512 + mt * 4096);      \
    PR[m4] = *(const bf16x8*)(prow + mt * 32);            \
  }                                                       \
  SB;
#define MMV(V0, V1, PR)                                                                      \
  _Pragma("unroll") for (int m4 = 0; m4 < 4; m4++) {                                         \
    dacc[0] = __builtin_amdgcn_mfma_f32_16x16x32_bf16(V0[m4], PR[m4], dacc[0], 0, 0, 0);     \
    dacc[1] = __builtin_amdgcn_mfma_f32_16x16x32_bf16(V1[m4], PR[m4], dacc[1], 0, 0, 0);     \
  }                                                                                          \
  SB;

  LDV(VA0, VA1, PAr, 0)
  LDV(VB0, VB1, PBr, 1)
  MMV(VA0, VA1, PAr) LDV(VA0, VA1, PAr, 2)
  MMV(VB0, VB1, PBr) LDV(VB0, VB1, PBr, 3)
  MMV(VA0, VA1, PAr) LDV(VA0, VA1, PAr, 4)
  MMV(VB0, VB1, PBr) LDV(VB0, VB1, PBr, 5)
  MMV(VA0, VA1, PAr) LDV(VA0, VA1, PAr, 6)
  MMV(VB0, VB1, PBr) LDV(VB0, VB1, PBr, 7)
  MMV(VA0, VA1, PAr)
  MMV(VB0, VB1, PBr)
#undef LDV
#undef MMV
  __syncthreads();

  float* Osh = (float*)Psh;
  short* Osh2 = Psh + 4352;
#pragma unroll
  for (int i = 0; i < 2; i++) {
    int cob = wv * 32 + i * 16 + quad * 4;
#pragma unroll
    for (int r = 0; r < 4; r++) Osh[(cob + r) * 17 + l16] = dacc[i][r];
  }
  __syncthreads();
  float g = gamma[sidx[b]];
  {
    int co = t >> 1, j0 = (t & 1) * 8;
    float sv = stat[(b * 128 + co) * 2 + 0];
    float sq = stat[(b * 128 + co) * 2 + 1];
    float mm = sv * (1.0f / 1024.0f);
    float iv = rsqrtf(sq * (1.0f / 1024.0f) - mm * mm + 1e-5f);
    const float* xr = xb + (co << 10) + n0 + j0;
    float4 xv0 = *(const float4*)xr;
    float4 xv1 = *(const float4*)(xr + 4);
    float xs[8] = {xv0.x, xv0.y, xv0.z, xv0.w, xv1.x, xv1.y, xv1.z, xv1.w};
#pragma unroll
    for (int j = 0; j < 8; j++) {
      float nv = (xs[j] - mm) * iv;
      xs[j] = LRELU(nv);
    }
#pragma unroll
    for (int j = 0; j < 8; j++) {
      int nl = j0 + j;
      float rs = 1.0f / (reds[nl] + reds[16 + nl] + reds[32 + nl] + reds[48 + nl]);
      Osh2[nl * 136 + co] = f2bf(g * Osh[co * 17 + nl] * rs + xs[j]);
    }
  }
  __syncthreads();
  {
    int nl = t >> 4, cg = t & 15;
    bf16x8 u = *(const bf16x8*)&Osh2[nl * 136 + cg * 8];
    int p = n0 + nl;
    int ih = p >> 5, iw = p & 31;
    *(bf16x8*)(ybf + ((size_t)b * 1156 + (ih + 1) * 34 + (iw + 1)) * 128 + cg * 8) = u;
  }
}

// ---------------------------------------------------------------------------
// conv2: LDS-staged MFMA GEMM. 1-D grid 512, XCD-swizzled like conv1.
__global__ __launch_bounds__(256, 2) void k_conv2n(
    const unsigned short* __restrict__ ybf, const unsigned short* __restrict__ wr,
    const int* __restrict__ sidx, float* __restrict__ x2) {
  __shared__ __align__(16) unsigned short Xs[26624];
  const int t = threadIdx.x;
  const int c = blockIdx.x & 7, rr = blockIdx.x >> 3;
  const int b = c + 8 * (rr >> 5);
  const int y = rr & 31;
  const int ne = y & 7;
  const int cog = y >> 3;
  const int s = sidx[b];
  const int lane = t & 63, wv = t >> 6;
  const int quad = lane >> 4, l16 = lane & 15;

  const unsigned short* gb = ybf + ((size_t)b * 1156 + 4 * ne * 34) * 128;
  {
    float4 v[13];
#pragma unroll
    for (int i = 0; i < 13; i++) v[i] = *(const float4*)(gb + (i * 256 + t) * 8);
#pragma unroll
    for (int i = 0; i < 13; i++) {
      int ba = (i * 256 + t) * 16;
      int sw = ba ^ (((ba >> 9) & 7) << 4);
      *(float4*)((char*)Xs + sw) = v[i];
    }
  }
  __syncthreads();

  const int co0w = cog * 64 + wv * 16;
  const unsigned short* ap = wr + ((size_t)(s * 256 + co0w + l16)) * 2048 + quad * 8;
  f32x4 acc[2];
  acc[0] = (f32x4){0.f, 0.f, 0.f, 0.f};
  acc[1] = (f32x4){0.f, 0.f, 0.f, 0.f};

#pragma unroll
  for (int kc = 0; kc < 64; kc++) {
    const int tap = kc >> 2;
    const int cio = (kc & 3) * 32 + quad * 8;
    const int kh = tap >> 2, kw = tap & 3;
    bf16x8 af = *(const bf16x8*)(ap + kc * 32);
#pragma unroll
    for (int nt = 0; nt < 2; nt++) {
      int lr = 2 * nt + kh;
      int col = 2 * l16 + kw;
      int ba = ((lr * 34 + col) * 128 + cio) * 2;
      int sw = ba ^ (((ba >> 9) & 7) << 4);
      bf16x8 bv = *(const bf16x8*)((const char*)Xs + sw);
      acc[nt] = __builtin_amdgcn_mfma_f32_16x16x32_bf16(af, bv, acc[nt], 0, 0, 0);
    }
  }

#pragma unroll
  for (int nt = 0; nt < 2; nt++) {
    int p = ne * 32 + nt * 16 + l16;
#pragma unroll
    for (int r = 0; r < 4; r++)
      x2[((size_t)b * 256 + co0w + quad * 4 + r) * 256 + p] = acc[nt][r];
  }
}

// ---------------------------------------------------------------------------
// head: x2 instance-norm (+leaky) FUSED into the head conv (x2 arrives RAW).
__global__ __launch_bounds__(256) void k_head_part(
    const float* __restrict__ x2, const float* __restrict__ wh,
    const int* __restrict__ sidx, float* __restrict__ out) {
  __shared__ float Xs[32 * 256];
  __shared__ float Wsh[512];
  __shared__ float sm[32], si[32];
  const int t = threadIdx.x;
  const int b = blockIdx.x, cc = blockIdx.y;
  const int s = sidx[b];
  const float* xp = x2 + ((size_t)b * 256 + cc * 32) * 256;
#pragma unroll
  for (int i = 0; i < 32; i++) Xs[i * 256 + t] = xp[i * 256 + t];
#pragma unroll
  for (int i = 0; i < 2; i++) {
    int idx = i * 256 + t;
    Wsh[idx] = wh[s * 4096 + cc * 512 + idx];
  }
  __syncthreads();
  {
    int r = t >> 3, c0 = (t & 7) * 32;
    float sv = 0.f, sq = 0.f;
#pragma unroll
    for (int j = 0; j < 32; j++) {
      float v = Xs[r * 256 + c0 + j];
      sv += v;
      sq += v * v;
    }
#pragma unroll
    for (int o = 1; o < 8; o <<= 1) {
      sv += __shfl_xor(sv, o, 64);
      sq += __shfl_xor(sq, o, 64);
    }
    if ((t & 7) == 0) {
      float m = sv * (1.0f / 256.0f);
      float var = sq * (1.0f / 256.0f) - m * m;
      sm[r] = m;
      si[r] = rsqrtf(var + 1e-5f);
    }
  }
  __syncthreads();
#pragma unroll
  for (int i = 0; i < 32; i++) {
    float v = (Xs[i * 256 + t] - sm[i]) * si[i];
    Xs[i * 256 + t] = LRELU(v);
  }
  __syncthreads();
  if (t < 225) {
    int oh = t / 15, ow = t % 15;
    float acc = 0.0f;
    for (int ci = 0; ci < 32; ci++) {
      const float* xr = Xs + ci * 256;
      const float* wr = Wsh + ci * 16;
#pragma unroll
      for (int kh = 0; kh < 4; kh++) {
        int ih = oh - 1 + kh;
        if ((unsigned)ih >= 16u) continue;
#pragma unroll
        for (int kw = 0; kw < 4; kw++) {
          int iw = ow - 1 + kw;
          if ((unsigned)iw >= 16u) continue;
          acc += wr[kh * 4 + kw] * xr[(ih << 4) + iw];
        }
      }
    }
    atomicAdd(out + b * 225 + t, acc);
  }
}

// ---------------------------------------------------------------------------
extern "C" void kernel_launch(void* const* d_in, const int* in_sizes, int n_in,
                              void* d_out, int out_size, void* d_ws, size_t ws_size,
                              hipStream_t stream) {
  const float* img = (const float*)d_in[0];
  const int* sidx = (const int*)d_in[1];
  const float* w0 = (const float*)d_in[2];
  const float* b0 = (const float*)d_in[3];
  const float* w1 = (const float*)d_in[4];
  const float* w2 = (const float*)d_in[6];
  const float* wq = (const float*)d_in[8];
  const float* bq = (const float*)d_in[9];
  const float* wk = (const float*)d_in[10];
  const float* bk = (const float*)d_in[11];
  const float* wv = (const float*)d_in[12];
  const float* bv = (const float*)d_in[13];
  const float* gamma = (const float*)d_in[14];
  const float* wh = (const float*)d_in[15];
  const float* bh = (const float*)d_in[16];
  float* out = (float*)d_out;

  float* ws = (float*)d_ws;
  unsigned short* x0t = (unsigned short*)(ws);            // padded 66x66: 16*4356*64 shorts
  float* x1 = ws + 2359296;                               // [2.25M,4.25M)
  unsigned short* qbf = (unsigned short*)(ws + 4456448);  // 16*1024*16 bf16 = 512KB
  unsigned short* kbf = (unsigned short*)(ws + 4718592);  // 16*1024*16 bf16 = 512KB
  unsigned short* vpk = (unsigned short*)(ws + 4980736);  // [4.75M,5.75M)
  unsigned short* ybf = (unsigned short*)(ws + 6029312);  // padded 34x34: 16*1156*128 shorts
  float* x2 = ws + 7340032;                               // [7M,8M)
  float* stat = ws + 8650752;                             // [8.25M,+4096) x1 norm stats
  unsigned short* wr1 = (unsigned short*)(ws + 8912896);  // [8.5M,8.75M)
  unsigned short* wr2 = (unsigned short*)(ws + 9175040);  // [8.75M,9.75M)

  k_repack_all<<<6949, 256, 0, stream>>>(w1, wr1, w2, wr2, bh, sidx, out, x0t, ybf,
                                         img, w0, b0, stat);
  k_conv1n<<<512, 256, 0, stream>>>(x0t, wr1, sidx, x1, stat);
  k_proj_qkv<<<640, 256, 0, stream>>>(x1, wq, bq, wk, bk, wv, bv, sidx, stat, qbf, kbf, vpk);
  k_attn<<<1024, 256, 0, stream>>>(qbf, kbf, vpk, x1, gamma, sidx, stat, ybf);
  k_conv2n<<<512, 256, 0, stream>>>(ybf, wr2, sidx, x2);
  k_head_part<<<dim3(16, 8), 256, 0, stream>>>(x2, wh, sidx, out);
}

// Round 15
// 196.639 us; speedup vs baseline: 1.0185x; 1.0059x over previous
//
#include <hip/hip_runtime.h>

#define LRELU(x) ((x) > 0.0f ? (x) : 0.2f * (x))
#define SB __builtin_amdgcn_sched_barrier(0)

typedef short bf16x8 __attribute__((ext_vector_type(8)));
typedef short bf16x4 __attribute__((ext_vector_type(4)));
typedef float f32x4 __attribute__((ext_vector_type(4)));

__device__ __forceinline__ short f2bf(float f) {
  union { float f; unsigned u; } x{f};
  return (short)((x.u + 0x7FFF + ((x.u >> 16) & 1)) >> 16);
}

// ---------------------------------------------------------------------------
// fused prologue: weight repack (float4-vectorized coalesced reads) +
// head-bias out init + border zeroing + x1-stat zeroing + conv0 (>= 2853).
// conv0 segment is XCD-ALIGNED with conv1n: block i (XCD=(2853+i)%8) handles
// batch b = ((i&7)+5)&7 + 8*(i>>11), so x0t[b] lands in XCD b%8's L2.
__global__ __launch_bounds__(256) void k_repack_all(
    const float* __restrict__ w1, unsigned short* __restrict__ wr1,
    const float* __restrict__ w2, unsigned short* __restrict__ wr2,
    const float* __restrict__ bh, const int* __restrict__ sidx,
    float* __restrict__ out, unsigned short* __restrict__ x0t,
    unsigned short* __restrict__ ybf, const float* __restrict__ img,
    const float* __restrict__ w0, const float* __restrict__ b0,
    float* __restrict__ stat) {
  __shared__ float Ish[4 * 34];
  if (blockIdx.x >= 2853) {
    // ---- conv0 segment: img (B,1,128,128) -> x0t padded 66x66 NHWC bf16
    const int t = threadIdx.x;
    const int i = blockIdx.x - 2853;
    const int b = (((i & 7) + 5) & 7) + 8 * (i >> 11);
    const int py = (i >> 3) & 255;
    const int oh = py >> 2, owb = (py & 3) << 4;
    const int s = sidx[b];
    const float* ip = img + (size_t)b * 16384;
    if (t < 136) {
      int r = t / 34, c = t % 34;
      int ih = 2 * oh - 1 + r, iw = 2 * owb - 1 + c;
      Ish[t] = ((unsigned)ih < 128u && (unsigned)iw < 128u) ? ip[ih * 128 + iw] : 0.f;
    }
    const int co = t & 63, ps = t >> 6;
    float wreg[16];
    const float* wp = w0 + (s * 64 + co) * 16;
#pragma unroll
    for (int j = 0; j < 16; j++) wreg[j] = wp[j];
    float bb = b0[s * 64 + co];
    __syncthreads();
    unsigned short* op = x0t + ((size_t)b * 4356 + (oh + 1) * 66 + (owb + 1)) * 64 + co;
#pragma unroll
    for (int j = 0; j < 4; j++) {
      int pl = ps * 4 + j;
      float acc = bb;
#pragma unroll
      for (int kh = 0; kh < 4; kh++)
#pragma unroll
        for (int kw = 0; kw < 4; kw++)
          acc += wreg[kh * 4 + kw] * Ish[kh * 34 + pl * 2 + kw];
      acc = LRELU(acc);
      op[pl * 64] = (unsigned short)f2bf(acc);
    }
    return;
  }
  int idx = blockIdx.x * 256 + threadIdx.x;
  if (idx < 131072) {
    float4 v = *(const float4*)(w1 + (size_t)idx * 4);
    int base = idx * 4;
    int tap0 = base & 15;
    int rest = base >> 4;
    int ci = rest & 63, sco = rest >> 6;
    unsigned short* d = wr1 + (size_t)sco * 1024 + ci;
    d[(tap0 + 0) * 64] = (unsigned short)f2bf(v.x);
    d[(tap0 + 1) * 64] = (unsigned short)f2bf(v.y);
    d[(tap0 + 2) * 64] = (unsigned short)f2bf(v.z);
    d[(tap0 + 3) * 64] = (unsigned short)f2bf(v.w);
    return;
  } else if (idx < 655360) {
    int i = idx - 131072;
    float4 v = *(const float4*)(w2 + (size_t)i * 4);
    int base = i * 4;
    int tap0 = base & 15;
    int rest = base >> 4;
    int ci = rest & 127, sco = rest >> 7;
    unsigned short* d = wr2 + (size_t)sco * 2048 + ci;
    d[(tap0 + 0) * 128] = (unsigned short)f2bf(v.x);
    d[(tap0 + 1) * 128] = (unsigned short)f2bf(v.y);
    d[(tap0 + 2) * 128] = (unsigned short)f2bf(v.z);
    d[(tap0 + 3) * 128] = (unsigned short)f2bf(v.w);
    return;
  } else if (idx < 658960) {
    int i = idx - 655360;
    if (i < 3600) out[i] = bh[sidx[i / 225]];
    return;
  } else if (idx < 692240) {
    int i = idx - 658960;
    int b = i / 2080, r = i % 2080;
    int pix = r >> 3, sub = r & 7;
    int row, col;
    if (pix < 66) { row = 0; col = pix; }
    else if (pix < 132) { row = 65; col = pix - 66; }
    else { int qq = pix - 132; row = 1 + (qq >> 1); col = (qq & 1) * 65; }
    bf16x8 z = {0, 0, 0, 0, 0, 0, 0, 0};
    *(bf16x8*)(x0t + ((size_t)b * 4356 + row * 66 + col) * 64 + sub * 8) = z;
    return;
  } else if (idx < 726032) {
    int i = idx - 692240;
    if (i >= 33792) return;
    int b = i / 2112, r = i % 2112;
    int pix = r >> 4, sub = r & 15;
    int row, col;
    if (pix < 34) { row = 0; col = pix; }
    else if (pix < 68) { row = 33; col = pix - 34; }
    else { int qq = pix - 68; row = 1 + (qq >> 1); col = (qq & 1) * 33; }
    bf16x8 z = {0, 0, 0, 0, 0, 0, 0, 0};
    *(bf16x8*)(ybf + ((size_t)b * 1156 + row * 34 + col) * 128 + sub * 8) = z;
    return;
  } else {
    int i = idx - 726032;
    if (i < 4096) stat[i] = 0.f;
    return;
  }
}

// ---------------------------------------------------------------------------
// conv1: LDS-staged MFMA GEMM + stat accumulation. 1-D grid 512, XCD-swizzled.
__global__ __launch_bounds__(256, 2) void k_conv1n(
    const unsigned short* __restrict__ x0t, const unsigned short* __restrict__ wr,
    const int* __restrict__ sidx, float* __restrict__ x1,
    float* __restrict__ stat) {
  __shared__ __align__(16) unsigned short Xs[26624];
  const int t = threadIdx.x;
  const int c = blockIdx.x & 7, rr = blockIdx.x >> 3;
  const int b = c + 8 * (rr >> 5);
  const int y = rr & 31;
  const int ne = y & 15;
  const int cog = y >> 4;
  const int s = sidx[b];
  const int lane = t & 63, wv = t >> 6;
  const int quad = lane >> 4, l16 = lane & 15;

  const unsigned short* gb = x0t + ((size_t)b * 4356 + 4 * ne * 66) * 64;
  {
    float4 v[13];
#pragma unroll
    for (int i = 0; i < 13; i++) v[i] = *(const float4*)(gb + (i * 256 + t) * 8);
#pragma unroll
    for (int i = 0; i < 13; i++) {
      int ba = (i * 256 + t) * 16;
      int sw = ba ^ (((ba >> 9) & 7) << 4);
      *(float4*)((char*)Xs + sw) = v[i];
    }
  }
  __syncthreads();

  const int co0w = cog * 64 + wv * 16;
  const unsigned short* ap = wr + ((size_t)(s * 128 + co0w + l16)) * 1024 + quad * 8;
  f32x4 acc[4];
#pragma unroll
  for (int nt = 0; nt < 4; nt++) acc[nt] = (f32x4){0.f, 0.f, 0.f, 0.f};

#pragma unroll
  for (int kc = 0; kc < 32; kc++) {
    const int tap = kc >> 1;
    const int cio = (kc & 1) * 32 + quad * 8;
    const int kh = tap >> 2, kw = tap & 3;
    bf16x8 af = *(const bf16x8*)(ap + kc * 32);
#pragma unroll
    for (int nt = 0; nt < 4; nt++) {
      int lr = 2 * (nt >> 1) + kh;
      int col = 2 * ((nt & 1) * 16 + l16) + kw;
      int ba = ((lr * 66 + col) * 64 + cio) * 2;
      int sw = ba ^ (((ba >> 9) & 7) << 4);
      bf16x8 bv = *(const bf16x8*)((const char*)Xs + sw);
      acc[nt] = __builtin_amdgcn_mfma_f32_16x16x32_bf16(af, bv, acc[nt], 0, 0, 0);
    }
  }

#pragma unroll
  for (int r = 0; r < 4; r++) {
    float sv = acc[0][r] + acc[1][r] + acc[2][r] + acc[3][r];
    float sq = acc[0][r] * acc[0][r] + acc[1][r] * acc[1][r] +
               acc[2][r] * acc[2][r] + acc[3][r] * acc[3][r];
#pragma unroll
    for (int o = 1; o < 16; o <<= 1) {
      sv += __shfl_xor(sv, o, 64);
      sq += __shfl_xor(sq, o, 64);
    }
    if (l16 == 0) {
      int co = co0w + quad * 4 + r;
      atomicAdd(&stat[(b * 128 + co) * 2 + 0], sv);
      atomicAdd(&stat[(b * 128 + co) * 2 + 1], sq);
    }
  }

#pragma unroll
  for (int nt = 0; nt < 4; nt++) {
    int p = ne * 64 + (nt >> 1) * 32 + (nt & 1) * 16 + l16;
#pragma unroll
    for (int r = 0; r < 4; r++)
      x1[((size_t)b * 128 + co0w + quad * 4 + r) * 1024 + p] = acc[nt][r];
  }
}

// ---------------------------------------------------------------------------
// fused q/k/v 1x1 projections over RAW x1 (lazy norm). q/k emitted as
// PRE-PACKED bf16 MFMA fragments. 1-D grid 640, XCD-swizzled.
__global__ __launch_bounds__(256) void k_proj_qkv(
    const float* __restrict__ xin, const float* __restrict__ wq,
    const float* __restrict__ bq, const float* __restrict__ wk,
    const float* __restrict__ bk, const float* __restrict__ wv,
    const float* __restrict__ bv, const int* __restrict__ sidx,
    const float* __restrict__ stat,
    unsigned short* __restrict__ qbf, unsigned short* __restrict__ kbf,
    unsigned short* __restrict__ vpk) {
  __shared__ float xsh[32 * 256];
  __shared__ float wsh[16 * 32];
  __shared__ float msh[128], ish[128];
  const int t = threadIdx.x;
  const int c = blockIdx.x & 7, rr = blockIdx.x >> 3;
  const int half = (rr >= 40) ? 1 : 0;
  const int b = c + 8 * half;
  const int y = rr - half * 40;
  const int s = sidx[b];
  const int cg = t >> 6, ng = t & 63;
  const float* w;
  const float* bias;
  int co0, nn0, CO;
  if (y < 8) {
    w = (y < 4) ? wq : wk;
    bias = (y < 4) ? bq : bk;
    co0 = 0;
    nn0 = (y & 3) * 256;
    CO = 16;
  } else {
    w = wv;
    bias = bv;
    co0 = ((y - 8) >> 2) * 16;
    nn0 = ((y - 8) & 3) * 256;
    CO = 128;
  }
  if (t < 128) {
    float sv = stat[(b * 128 + t) * 2 + 0];
    float sq = stat[(b * 128 + t) * 2 + 1];
    float m = sv * (1.0f / 1024.0f);
    float var = sq * (1.0f / 1024.0f) - m * m;
    msh[t] = m;
    ish[t] = rsqrtf(var + 1e-5f);
  }
  const float* xb = xin + (size_t)b * 128 * 1024;
  float4 acc4[4];
#pragma unroll
  for (int cix = 0; cix < 4; cix++) {
    float bb = bias[s * CO + co0 + cg * 4 + cix];
    acc4[cix] = make_float4(bb, bb, bb, bb);
  }
  __syncthreads();
  for (int cc = 0; cc < 4; cc++) {
#pragma unroll
    for (int k = 0; k < 8; k++) {
      int id = t + (k << 8);
      int ci = id >> 6, nf = id & 63;
      float4 v = ((const float4*)(xb + (cc * 32 + ci) * 1024 + nn0))[nf];
      float m = msh[cc * 32 + ci], iv = ish[cc * 32 + ci];
      v.x = (v.x - m) * iv; v.x = LRELU(v.x);
      v.y = (v.y - m) * iv; v.y = LRELU(v.y);
      v.z = (v.z - m) * iv; v.z = LRELU(v.z);
      v.w = (v.w - m) * iv; v.w = LRELU(v.w);
      ((float4*)xsh)[id] = v;
    }
    if (t < 128)
      ((float4*)wsh)[t] =
          ((const float4*)(w + ((size_t)(s * CO + co0 + (t >> 3))) * 128 + cc * 32))[t & 7];
    __syncthreads();
#pragma unroll
    for (int ci4 = 0; ci4 < 8; ci4++) {
      float4 wvv[4], xv[4];
#pragma unroll
      for (int cix = 0; cix < 4; cix++) wvv[cix] = ((const float4*)wsh)[(cg * 4 + cix) * 8 + ci4];
#pragma unroll
      for (int i = 0; i < 4; i++) xv[i] = ((const float4*)xsh)[(ci4 * 4 + i) * 64 + ng];
#pragma unroll
      for (int cix = 0; cix < 4; cix++)
#pragma unroll
        for (int i = 0; i < 4; i++) {
          float wvc = i == 0 ? wvv[cix].x : i == 1 ? wvv[cix].y : i == 2 ? wvv[cix].z : wvv[cix].w;
          acc4[cix].x += wvc * xv[i].x;
          acc4[cix].y += wvc * xv[i].y;
          acc4[cix].z += wvc * xv[i].z;
          acc4[cix].w += wvc * xv[i].w;
        }
    }
    __syncthreads();
  }
  if (y < 8) {
    unsigned short* outp = ((y < 4) ? qbf : kbf) + (size_t)b * 16384;
#pragma unroll
    for (int j = 0; j < 4; j++) {
      bf16x4 u;
#pragma unroll
      for (int cix = 0; cix < 4; cix++) {
        float v = j == 0 ? acc4[cix].x : j == 1 ? acc4[cix].y : j == 2 ? acc4[cix].z
                                                                       : acc4[cix].w;
        u[cix] = f2bf(v);
      }
      *(bf16x4*)(outp + (size_t)(nn0 + ng * 4 + j) * 16 + cg * 4) = u;
    }
  } else {
    int n = nn0 + ng * 4;
#pragma unroll
    for (int cix = 0; cix < 4; cix++) {
      int co = co0 + cg * 4 + cix;
      bf16x4 u;
      u[0] = f2bf(acc4[cix].x);
      u[1] = f2bf(acc4[cix].y);
      u[2] = f2bf(acc4[cix].z);
      u[3] = f2bf(acc4[cix].w);
      *(bf16x4*)(vpk + (((size_t)b * 32 + (n >> 5)) * 128 + co) * 32 + (n & 31)) = u;
    }
  }
}

// ---------------------------------------------------------------------------
// fused self-attention; MFMA QK^T with PRE-PACKED bf16 q/k fragments.
// 1-D grid 1024, XCD-swizzled.
__global__ __launch_bounds__(256, 2) void k_attn(
    const unsigned short* __restrict__ qbf, const unsigned short* __restrict__ kbf,
    const unsigned short* __restrict__ vpk, const float* __restrict__ x1,
    const float* __restrict__ gamma, const int* __restrict__ sidx,
    const float* __restrict__ stat, unsigned short* __restrict__ ybf) {
  __shared__ __align__(16) short Psh[16 * 1032];
  __shared__ float redm[64], reds[64];
  const int t = threadIdx.x;
  const int c = blockIdx.x & 7, rr = blockIdx.x >> 3;
  const int b = c + 8 * (rr >> 6);
  const int n0 = (rr & 63) << 4;
  const int lane = t & 63, wv = t >> 6;
  const int quad = lane >> 4, l16 = lane & 15;
  const unsigned short* qbb = qbf + (size_t)b * 16384;
  const unsigned short* kbb = kbf + (size_t)b * 16384;
  const float* xb = x1 + (size_t)b * 128 * 1024;

  bf16x8 qf = {0, 0, 0, 0, 0, 0, 0, 0};
  if (quad < 2) qf = *(const bf16x8*)(qbb + (size_t)(n0 + l16) * 16 + quad * 8);

  f32x4 sacc[16];
#pragma unroll
  for (int tt = 0; tt < 16; tt++) sacc[tt] = (f32x4){0.f, 0.f, 0.f, 0.f};
  const int mwb = wv * 256;
#pragma unroll
  for (int tt = 0; tt < 16; tt++) {
    bf16x8 afr = {0, 0, 0, 0, 0, 0, 0, 0};
    if (quad < 2)
      afr = *(const bf16x8*)(kbb + (size_t)(mwb + tt * 16 + l16) * 16 + quad * 8);
    sacc[tt] = __builtin_amdgcn_mfma_f32_16x16x32_bf16(afr, qf, sacc[tt], 0, 0, 0);
  }

  float lmax = sacc[0][0];
#pragma unroll
  for (int tt = 0; tt < 16; tt++)
#pragma unroll
    for (int r = 0; r < 4; r++) lmax = fmaxf(lmax, sacc[tt][r]);
  lmax = fmaxf(lmax, __shfl_xor(lmax, 16, 64));
  lmax = fmaxf(lmax, __shfl_xor(lmax, 32, 64));
  if (lane < 16) redm[wv * 16 + lane] = lmax;
  __syncthreads();
  float gmax = fmaxf(fmaxf(redm[l16], redm[16 + l16]), fmaxf(redm[32 + l16], redm[48 + l16]));

  float lsum = 0.f;
#pragma unroll
  for (int tt = 0; tt < 16; tt++) {
    bf16x4 pv4;
#pragma unroll
    for (int r = 0; r < 4; r++) {
      float e = __expf(sacc[tt][r] - gmax);
      lsum += e;
      pv4[r] = f2bf(e);
    }
    *(bf16x4*)&Psh[l16 * 1032 + mwb + tt * 16 + quad * 4] = pv4;
  }
  lsum += __shfl_xor(lsum, 16, 64);
  lsum += __shfl_xor(lsum, 32, 64);
  if (lane < 16) reds[wv * 16 + lane] = lsum;
  __syncthreads();

  const unsigned short* vp =
      vpk + ((size_t)b * 32 * 128 + (size_t)(wv * 32 + l16)) * 32 + quad * 8;
  const short* prow = Psh + l16 * 1032 + quad * 8;
  f32x4 dacc[2];
  dacc[0] = (f32x4){0.f, 0.f, 0.f, 0.f};
  dacc[1] = (f32x4){0.f, 0.f, 0.f, 0.f};

  bf16x8 VA0[4], VA1[4], PAr[4];
  bf16x8 VB0[4], VB1[4], PBr[4];
#define LDV(V0, V1, PR, G)                                \
  _Pragma("unroll") for (int m4 = 0; m4 < 4; m4++) {      \
    int mt = (G) * 4 + m4;                                \
    V0[m4] = *(const bf16x8*)(vp + mt * 4096);            \
    V1[m4] = *(const bf16x8*)(vp + 512 + mt * 4096);      \
    PR[m4] = *(const bf16x8*)(prow + mt * 32);            \
  }                                                       \
  SB;
#define MMV(V0, V1, PR)                                                                      \
  _Pragma("unroll") for (int m4 = 0; m4 < 4; m4++) {                                         \
    dacc[0] = __builtin_amdgcn_mfma_f32_16x16x32_bf16(V0[m4], PR[m4], dacc[0], 0, 0, 0);     \
    dacc[1] = __builtin_amdgcn_mfma_f32_16x16x32_bf16(V1[m4], PR[m4], dacc[1], 0, 0, 0);     \
  }                                                                                          \
  SB;

  LDV(VA0, VA1, PAr, 0)
  LDV(VB0, VB1, PBr, 1)
  MMV(VA0, VA1, PAr) LDV(VA0, VA1, PAr, 2)
  MMV(VB0, VB1, PBr) LDV(VB0, VB1, PBr, 3)
  MMV(VA0, VA1, PAr) LDV(VA0, VA1, PAr, 4)
  MMV(VB0, VB1, PBr) LDV(VB0, VB1, PBr, 5)
  MMV(VA0, VA1, PAr) LDV(VA0, VA1, PAr, 6)
  MMV(VB0, VB1, PBr) LDV(VB0, VB1, PBr, 7)
  MMV(VA0, VA1, PAr)
  MMV(VB0, VB1, PBr)
#undef LDV
#undef MMV
  __syncthreads();

  float* Osh = (float*)Psh;
  short* Osh2 = Psh + 4352;
#pragma unroll
  for (int i = 0; i < 2; i++) {
    int cob = wv * 32 + i * 16 + quad * 4;
#pragma unroll
    for (int r = 0; r < 4; r++) Osh[(cob + r) * 17 + l16] = dacc[i][r];
  }
  __syncthreads();
  float g = gamma[sidx[b]];
  {
    int co = t >> 1, j0 = (t & 1) * 8;
    float sv = stat[(b * 128 + co) * 2 + 0];
    float sq = stat[(b * 128 + co) * 2 + 1];
    float mm = sv * (1.0f / 1024.0f);
    float iv = rsqrtf(sq * (1.0f / 1024.0f) - mm * mm + 1e-5f);
    const float* xr = xb + (co << 10) + n0 + j0;
    float4 xv0 = *(const float4*)xr;
    float4 xv1 = *(const float4*)(xr + 4);
    float xs[8] = {xv0.x, xv0.y, xv0.z, xv0.w, xv1.x, xv1.y, xv1.z, xv1.w};
#pragma unroll
    for (int j = 0; j < 8; j++) {
      float nv = (xs[j] - mm) * iv;
      xs[j] = LRELU(nv);
    }
#pragma unroll
    for (int j = 0; j < 8; j++) {
      int nl = j0 + j;
      float rs = 1.0f / (reds[nl] + reds[16 + nl] + reds[32 + nl] + reds[48 + nl]);
      Osh2[nl * 136 + co] = f2bf(g * Osh[co * 17 + nl] * rs + xs[j]);
    }
  }
  __syncthreads();
  {
    int nl = t >> 4, cg = t & 15;
    bf16x8 u = *(const bf16x8*)&Osh2[nl * 136 + cg * 8];
    int p = n0 + nl;
    int ih = p >> 5, iw = p & 31;
    *(bf16x8*)(ybf + ((size_t)b * 1156 + (ih + 1) * 34 + (iw + 1)) * 128 + cg * 8) = u;
  }
}

// ---------------------------------------------------------------------------
// conv2: LDS-staged MFMA GEMM. 1-D grid 512, XCD-swizzled like conv1.
__global__ __launch_bounds__(256, 2) void k_conv2n(
    const unsigned short* __restrict__ ybf, const unsigned short* __restrict__ wr,
    const int* __restrict__ sidx, float* __restrict__ x2) {
  __shared__ __align__(16) unsigned short Xs[26624];
  const int t = threadIdx.x;
  const int c = blockIdx.x & 7, rr = blockIdx.x >> 3;
  const int b = c + 8 * (rr >> 5);
  const int y = rr & 31;
  const int ne = y & 7;
  const int cog = y >> 3;
  const int s = sidx[b];
  const int lane = t & 63, wv = t >> 6;
  const int quad = lane >> 4, l16 = lane & 15;

  const unsigned short* gb = ybf + ((size_t)b * 1156 + 4 * ne * 34) * 128;
  {
    float4 v[13];
#pragma unroll
    for (int i = 0; i < 13; i++) v[i] = *(const float4*)(gb + (i * 256 + t) * 8);
#pragma unroll
    for (int i = 0; i < 13; i++) {
      int ba = (i * 256 + t) * 16;
      int sw = ba ^ (((ba >> 9) & 7) << 4);
      *(float4*)((char*)Xs + sw) = v[i];
    }
  }
  __syncthreads();

  const int co0w = cog * 64 + wv * 16;
  const unsigned short* ap = wr + ((size_t)(s * 256 + co0w + l16)) * 2048 + quad * 8;
  f32x4 acc[2];
  acc[0] = (f32x4){0.f, 0.f, 0.f, 0.f};
  acc[1] = (f32x4){0.f, 0.f, 0.f, 0.f};

#pragma unroll
  for (int kc = 0; kc < 64; kc++) {
    const int tap = kc >> 2;
    const int cio = (kc & 3) * 32 + quad * 8;
    const int kh = tap >> 2, kw = tap & 3;
    bf16x8 af = *(const bf16x8*)(ap + kc * 32);
#pragma unroll
    for (int nt = 0; nt < 2; nt++) {
      int lr = 2 * nt + kh;
      int col = 2 * l16 + kw;
      int ba = ((lr * 34 + col) * 128 + cio) * 2;
      int sw = ba ^ (((ba >> 9) & 7) << 4);
      bf16x8 bv = *(const bf16x8*)((const char*)Xs + sw);
      acc[nt] = __builtin_amdgcn_mfma_f32_16x16x32_bf16(af, bv, acc[nt], 0, 0, 0);
    }
  }

#pragma unroll
  for (int nt = 0; nt < 2; nt++) {
    int p = ne * 32 + nt * 16 + l16;
#pragma unroll
    for (int r = 0; r < 4; r++)
      x2[((size_t)b * 256 + co0w + quad * 4 + r) * 256 + p] = acc[nt][r];
  }
}

// ---------------------------------------------------------------------------
// head: x2 instance-norm (+leaky) FUSED into the head conv (x2 arrives RAW).
__global__ __launch_bounds__(256) void k_head_part(
    const float* __restrict__ x2, const float* __restrict__ wh,
    const int* __restrict__ sidx, float* __restrict__ out) {
  __shared__ float Xs[32 * 256];
  __shared__ float Wsh[512];
  __shared__ float sm[32], si[32];
  const int t = threadIdx.x;
  const int b = blockIdx.x, cc = blockIdx.y;
  const int s = sidx[b];
  const float* xp = x2 + ((size_t)b * 256 + cc * 32) * 256;
#pragma unroll
  for (int i = 0; i < 32; i++) Xs[i * 256 + t] = xp[i * 256 + t];
#pragma unroll
  for (int i = 0; i < 2; i++) {
    int idx = i * 256 + t;
    Wsh[idx] = wh[s * 4096 + cc * 512 + idx];
  }
  __syncthreads();
  {
    int r = t >> 3, c0 = (t & 7) * 32;
    float sv = 0.f, sq = 0.f;
#pragma unroll
    for (int j = 0; j < 32; j++) {
      float v = Xs[r * 256 + c0 + j];
      sv += v;
      sq += v * v;
    }
#pragma unroll
    for (int o = 1; o < 8; o <<= 1) {
      sv += __shfl_xor(sv, o, 64);
      sq += __shfl_xor(sq, o, 64);
    }
    if ((t & 7) == 0) {
      float m = sv * (1.0f / 256.0f);
      float var = sq * (1.0f / 256.0f) - m * m;
      sm[r] = m;
      si[r] = rsqrtf(var + 1e-5f);
    }
  }
  __syncthreads();
#pragma unroll
  for (int i = 0; i < 32; i++) {
    float v = (Xs[i * 256 + t] - sm[i]) * si[i];
    Xs[i * 256 + t] = LRELU(v);
  }
  __syncthreads();
  if (t < 225) {
    int oh = t / 15, ow = t % 15;
    float acc = 0.0f;
    for (int ci = 0; ci < 32; ci++) {
      const float* xr = Xs + ci * 256;
      const float* wr = Wsh + ci * 16;
#pragma unroll
      for (int kh = 0; kh < 4; kh++) {
        int ih = oh - 1 + kh;
        if ((unsigned)ih >= 16u) continue;
#pragma unroll
        for (int kw = 0; kw < 4; kw++) {
          int iw = ow - 1 + kw;
          if ((unsigned)iw >= 16u) continue;
          acc += wr[kh * 4 + kw] * xr[(ih << 4) + iw];
        }
      }
    }
    atomicAdd(out + b * 225 + t, acc);
  }
}

// ---------------------------------------------------------------------------
extern "C" void kernel_launch(void* const* d_in, const int* in_sizes, int n_in,
                              void* d_out, int out_size, void* d_ws, size_t ws_size,
                              hipStream_t stream) {
  const float* img = (const float*)d_in[0];
  const int* sidx = (const int*)d_in[1];
  const float* w0 = (const float*)d_in[2];
  const float* b0 = (const float*)d_in[3];
  const float* w1 = (const float*)d_in[4];
  const float* w2 = (const float*)d_in[6];
  const float* wq = (const float*)d_in[8];
  const float* bq = (const float*)d_in[9];
  const float* wk = (const float*)d_in[10];
  const float* bk = (const float*)d_in[11];
  const float* wv = (const float*)d_in[12];
  const float* bv = (const float*)d_in[13];
  const float* gamma = (const float*)d_in[14];
  const float* wh = (const float*)d_in[15];
  const float* bh = (const float*)d_in[16];
  float* out = (float*)d_out;

  float* ws = (float*)d_ws;
  unsigned short* x0t = (unsigned short*)(ws);            // padded 66x66: 16*4356*64 shorts
  float* x1 = ws + 2359296;                               // [2.25M,4.25M)
  unsigned short* qbf = (unsigned short*)(ws + 4456448);  // 16*1024*16 bf16 = 512KB
  unsigned short* kbf = (unsigned short*)(ws + 4718592);  // 16*1024*16 bf16 = 512KB
  unsigned short* vpk = (unsigned short*)(ws + 4980736);  // [4.75M,5.75M)
  unsigned short* ybf = (unsigned short*)(ws + 6029312);  // padded 34x34: 16*1156*128 shorts
  float* x2 = ws + 7340032;                               // [7M,8M)
  float* stat = ws + 8650752;                             // [8.25M,+4096) x1 norm stats
  unsigned short* wr1 = (unsigned short*)(ws + 8912896);  // [8.5M,8.75M)
  unsigned short* wr2 = (unsigned short*)(ws + 9175040);  // [8.75M,9.75M)

  k_repack_all<<<6949, 256, 0, stream>>>(w1, wr1, w2, wr2, bh, sidx, out, x0t, ybf,
                                         img, w0, b0, stat);
  k_conv1n<<<512, 256, 0, stream>>>(x0t, wr1, sidx, x1, stat);
  k_proj_qkv<<<640, 256, 0, stream>>>(x1, wq, bq, wk, bk, wv, bv, sidx, stat, qbf, kbf, vpk);
  k_attn<<<1024, 256, 0, stream>>>(qbf, kbf, vpk, x1, gamma, sidx, stat, ybf);
  k_conv2n<<<512, 256, 0, stream>>>(ybf, wr2, sidx, x2);
  k_head_part<<<dim3(16, 8), 256, 0, stream>>>(x2, wh, sidx, out);
}